// Round 2
// baseline (268.743 us; speedup 1.0000x reference)
//
#include <hip/hip_runtime.h>

// img: [B=256, C=3, H=224, W=224] fp32; y_idx/x_idx: [B] int32; square 32x32.
// Strategy: (1) dumb streaming copy at fill speed, (2) tiny kernel zeroing
// the 256*3*32*32*4B = 3.1 MB of squares. Avoids per-element index math on
// the 308 MB hot path.

#define SQ 32
#define B_ 256
#define C_ 3
#define H_ 224
#define W_ 224
#define IMG_ELEMS (C_ * H_ * W_)   // 150528 per batch

// ---- Kernel 1: streaming copy, 4 float4 (64B) per thread ----------------
// total4 = 9,633,792 float4s; 4 per thread -> 2,408,448 threads -> 9408 blocks.
// Access pattern: lane-contiguous float4 per step (16B/lane coalescing).
__global__ __launch_bounds__(256) void copy_kernel(const float4* __restrict__ src,
                                                   float4* __restrict__ dst,
                                                   int total4) {
    int base = blockIdx.x * (256 * 4) + threadIdx.x;
#pragma unroll
    for (int k = 0; k < 4; ++k) {
        int i = base + k * 256;
        if (i < total4) dst[i] = src[i];
    }
}

// ---- Kernel 2: zero the squares ----------------------------------------
// One block per batch. 3 channels * 32 rows * 32 cols = 3072 floats/batch.
// idx -> c = idx/1024, dy = (idx%1024)/32, dx = idx%32  (all pow2 shifts).
__global__ __launch_bounds__(256) void zero_kernel(const int* __restrict__ y_idx,
                                                   const int* __restrict__ x_idx,
                                                   float* __restrict__ out) {
    int b  = blockIdx.x;
    int y0 = y_idx[b];
    int x0 = x_idx[b];
    float* img = out + (size_t)b * IMG_ELEMS;
#pragma unroll
    for (int t = 0; t < 12; ++t) {            // 3072 / 256 = 12
        int idx = t * 256 + threadIdx.x;
        int c   = idx >> 10;                  // /1024
        int dy  = (idx >> 5) & 31;            // (%1024)/32
        int dx  = idx & 31;                   // %32
        img[(c * H_ + y0 + dy) * W_ + x0 + dx] = 0.0f;
    }
}

extern "C" void kernel_launch(void* const* d_in, const int* in_sizes, int n_in,
                              void* d_out, int out_size, void* d_ws, size_t ws_size,
                              hipStream_t stream) {
    const float4* img  = (const float4*)d_in[0];
    const int*    yidx = (const int*)d_in[1];
    const int*    xidx = (const int*)d_in[2];

    int total4 = out_size / 4;                     // 9,633,792
    int blocks = (total4 + (256 * 4) - 1) / (256 * 4);  // 9408
    copy_kernel<<<blocks, 256, 0, stream>>>(img, (float4*)d_out, total4);
    zero_kernel<<<B_, 256, 0, stream>>>(yidx, xidx, (float*)d_out);
}